// Round 13
// baseline (1582.053 us; speedup 1.0000x reference)
//
#include <hip/hip_runtime.h>
#include <hip/hip_cooperative_groups.h>
#include <stdint.h>

namespace cg = cooperative_groups;

// NCA: B=8, C=16, H=W=128, hidden=128, 8 steps.
// ws: [0,8MB) midA, [8MB,16MB) midB, [+512KB) mid3c, [+128KB) pre,
//     [+2MB) mask bits, [+24KB) w1T, [+8KB) w2T. ~18.7 MB.

#define BATCH 8
#define CH 16
#define HT 128
#define WD 128
#define HIDN 128
#define PLANE (HT*WD)
#define IMG (CH*PLANE)
#define NELEM (BATCH*IMG)
#define NPIX (BATCH*PLANE)
#define WORDS_PER_STEP (NELEM/32)   // 65536
#define NSTEPS 8
#define NPIXB 64     // pixels per step_a group (half row)
#define NGRP (NPIX/NPIXB)           // 2048
#define RROW 65      // red row stride: odd -> conflict-free

struct Keys { unsigned k[2*NSTEPS]; };

__host__ __device__ __forceinline__ unsigned rotl32u(unsigned v, int r) {
  return (v << r) | (v >> (32 - r));
}

// JAX threefry2x32 (20 rounds).
__host__ __device__ __forceinline__ void tf2x32(unsigned k0, unsigned k1,
                                                unsigned c0, unsigned c1,
                                                unsigned &o0, unsigned &o1) {
  const unsigned ks2 = k0 ^ k1 ^ 0x1BD11BDAu;
  unsigned x0 = c0 + k0, x1 = c1 + k1;
  x0 += x1; x1 = rotl32u(x1, 13); x1 ^= x0;
  x0 += x1; x1 = rotl32u(x1, 15); x1 ^= x0;
  x0 += x1; x1 = rotl32u(x1, 26); x1 ^= x0;
  x0 += x1; x1 = rotl32u(x1,  6); x1 ^= x0;
  x0 += k1; x1 += ks2 + 1u;
  x0 += x1; x1 = rotl32u(x1, 17); x1 ^= x0;
  x0 += x1; x1 = rotl32u(x1, 29); x1 ^= x0;
  x0 += x1; x1 = rotl32u(x1, 16); x1 ^= x0;
  x0 += x1; x1 = rotl32u(x1, 24); x1 ^= x0;
  x0 += ks2; x1 += k0 + 2u;
  x0 += x1; x1 = rotl32u(x1, 13); x1 ^= x0;
  x0 += x1; x1 = rotl32u(x1, 15); x1 ^= x0;
  x0 += x1; x1 = rotl32u(x1, 26); x1 ^= x0;
  x0 += x1; x1 = rotl32u(x1,  6); x1 ^= x0;
  x0 += k0; x1 += k1 + 3u;
  x0 += x1; x1 = rotl32u(x1, 17); x1 ^= x0;
  x0 += x1; x1 = rotl32u(x1, 29); x1 ^= x0;
  x0 += x1; x1 = rotl32u(x1, 16); x1 ^= x0;
  x0 += x1; x1 = rotl32u(x1, 24); x1 ^= x0;
  x0 += k1; x1 += ks2 + 4u;
  x0 += x1; x1 = rotl32u(x1, 13); x1 ^= x0;
  x0 += x1; x1 = rotl32u(x1, 15); x1 ^= x0;
  x0 += x1; x1 = rotl32u(x1, 26); x1 ^= x0;
  x0 += x1; x1 = rotl32u(x1,  6); x1 ^= x0;
  x0 += ks2; x1 += k0 + 5u;
  o0 = x0; o1 = x1;
}

// ---- device bodies (shared by coop kernel and fallback wrappers) ----

__device__ __forceinline__ void mask_word_body(unsigned* __restrict__ mask,
                                               unsigned k0, unsigned k1,
                                               unsigned w) {
  unsigned base = w << 5;
  unsigned word = 0u;
  #pragma unroll 4
  for (int i = 0; i < 32; ++i) {
    unsigned b1x, b2x;
    tf2x32(k0, k1, 0u, base + (unsigned)i, b1x, b2x);
    word |= ((((b1x ^ b2x) >> 9) != 0u) ? 1u : 0u) << i;
  }
  mask[w] = word;
}

__device__ __forceinline__ void wpack_body(int t,
    const float* __restrict__ w1, const float* __restrict__ w2,
    float* __restrict__ w1T, float* __restrict__ w2T) {
  if (t < 48 * HIDN) {
    int c = t >> 7, h = t & 127;
    w1T[t] = w1[h * 48 + c];
  } else {
    int i = t - 48 * HIDN;
    int h = i >> 4, o = i & 15;
    w2T[i] = w2[o * HIDN + h];
  }
}

// r12's measured-best step_a body, parameterized by group id.
__device__ __forceinline__ void step_a_body(
    int grp, int tid,
    const float* __restrict__ s,
    const float* __restrict__ w1T, const float* __restrict__ w2T,
    const float* __restrict__ bias1, const float* __restrict__ bias2,
    const unsigned* __restrict__ mask,
    float* __restrict__ mid, float* __restrict__ mid3c,
    unsigned char* __restrict__ pre,
    float (*plds)[NPIXB], float* red) {
  const int pix = tid & 63;
  const int g = __builtin_amdgcn_readfirstlane(tid >> 6);  // wave-uniform 0..7
  const int pid = grp * NPIXB + pix;
  const int b = pid >> 14;
  const int r = pid & 16383;
  const int y = r >> 7, x = r & 127;

  const float* sb = s + b * IMG;
  const int ctr = y * WD + x;
  const bool yu = (y > 0), yd = (y < HT - 1), xl = (x > 0), xr = (x < WD - 1);
  float premax = -1e30f;
  #pragma unroll
  for (int cc = 0; cc < 2; ++cc) {
    const int c = 2 * g + cc;
    const float* sc = sb + c * PLANE + ctr;
    float a11 = sc[0];
    float a00 = (yu && xl) ? sc[-WD - 1] : 0.f;
    float a01 = yu         ? sc[-WD]     : 0.f;
    float a02 = (yu && xr) ? sc[-WD + 1] : 0.f;
    float a10 = xl         ? sc[-1]      : 0.f;
    float a12 = xr         ? sc[1]       : 0.f;
    float a20 = (yd && xl) ? sc[WD - 1]  : 0.f;
    float a21 = yd         ? sc[WD]      : 0.f;
    float a22 = (yd && xr) ? sc[WD + 1]  : 0.f;
    plds[c][pix]      = a11;
    plds[16 + c][pix] = (a02 - a00) + 2.f * (a12 - a10) + (a22 - a20);
    plds[32 + c][pix] = (a20 - a00) + 2.f * (a21 - a01) + (a22 - a02);
    if (g == 1 && cc == 1) {           // c == 3, the alive channel
      float m0 = fmaxf(fmaxf(a00, a01), fmaxf(a02, a10));
      float m1 = fmaxf(fmaxf(a11, a12), fmaxf(a20, a21));
      premax = fmaxf(fmaxf(m0, m1), a22);
    }
  }
  __syncthreads();

  float t16[16];
  {
    const float* b1c = bias1 + g * 16;
    #pragma unroll
    for (int j = 0; j < 16; ++j) t16[j] = b1c[j];
  }
  #pragma unroll 2
  for (int c = 0; c < 48; ++c) {
    const float pc = plds[c][pix];             // ds_read_b32, conflict-free
    const float* wr = w1T + c * HIDN + g * 16; // s_load_dwordx16
    #pragma unroll
    for (int j = 0; j < 16; ++j) t16[j] = fmaf(pc, wr[j], t16[j]);
  }
  float dx[16];
  #pragma unroll
  for (int o = 0; o < 16; ++o) dx[o] = 0.f;
  #pragma unroll
  for (int j = 0; j < 16; ++j) {
    float h = fmaxf(t16[j], 0.f);
    const float* w2r = w2T + (g * 16 + j) * 16;  // s_load_dwordx16
    #pragma unroll
    for (int o = 0; o < 16; ++o) dx[o] = fmaf(h, w2r[o], dx[o]);
  }

  if (g < 4) {
    #pragma unroll
    for (int o = 0; o < 16; ++o) red[pix * RROW + g * 16 + o] = dx[o];
  }
  __syncthreads();
  if (g >= 4) {
    #pragma unroll
    for (int o = 0; o < 16; ++o) red[pix * RROW + (g - 4) * 16 + o] += dx[o];
  }
  if (g == 1) pre[pid] = (premax > 0.1f) ? 1 : 0;
  __syncthreads();

  #pragma unroll
  for (int k = 0; k < 2; ++k) {
    const int idx = tid + k * 512;
    const int p2 = idx & 63, o = idx >> 6;
    const int pid2 = grp * NPIXB + p2;
    const int b2i = pid2 >> 14;
    const int r2 = pid2 & 16383;
    const int y2 = r2 >> 7, x2 = r2 & 127;
    const float* rr = red + p2 * RROW + o;
    float d = ((rr[0] + rr[16]) + (rr[32] + rr[48])) + bias2[o];
    d = fminf(fmaxf(d, -5.f), 5.f);
    unsigned mw = mask[((b2i * 16 + o) * HT + y2) * 4 + (x2 >> 5)];
    float v = plds[o][p2] + (((mw >> (x2 & 31)) & 1u) ? d : 0.f);
    mid[b2i * IMG + o * PLANE + r2] = v;
    if (o == 3) mid3c[pid2] = v;     // ch3 snapshot for fmaskzero
  }
}

__device__ __forceinline__ void fmaskzero_body(int t,
    const float* __restrict__ mid3c, const unsigned char* __restrict__ pre,
    float* __restrict__ mid) {
  int b = t >> 14;
  int r = t & 16383;
  int y = r >> 7, x = r & 127;
  const float* m3 = mid3c + b * PLANE;
  float mx = -1e30f;
  #pragma unroll
  for (int dy = -1; dy <= 1; ++dy) {
    int yy = y + dy; if ((unsigned)yy >= HT) continue;
    #pragma unroll
    for (int dxx = -1; dxx <= 1; ++dxx) {
      int xx = x + dxx;
      if ((unsigned)xx < WD) mx = fmaxf(mx, m3[yy * WD + xx]);
    }
  }
  if (!((mx > 0.1f) && pre[t])) {
    float* mp = mid + b * IMG + r;
    #pragma unroll
    for (int c = 0; c < CH; ++c) mp[c * PLANE] = 0.f;
  }
}

__device__ __forceinline__ void step_b_body(int t,
    const float* __restrict__ mid, const unsigned char* __restrict__ pre,
    float* __restrict__ out) {
  int cq = t >> 15;
  int qid = t & 32767;
  int b = qid >> 12;
  int r = qid & 4095;
  int y = r >> 5;
  int x0 = (r & 31) * 4;
  const float* m3 = mid + b * IMG + 3 * PLANE;

  float col[6];
  #pragma unroll
  for (int j = 0; j < 6; ++j) {
    int xx = x0 - 1 + j;
    float m = -1e30f;
    if ((unsigned)xx < WD) {
      #pragma unroll
      for (int dy = -1; dy <= 1; ++dy) {
        int yy = y + dy;
        if ((unsigned)yy < HT) m = fmaxf(m, m3[yy * WD + xx]);
      }
    }
    col[j] = m;
  }
  const unsigned char* pr = pre + b * PLANE + y * WD + x0;
  float f[4];
  #pragma unroll
  for (int i = 0; i < 4; ++i) {
    float mx = fmaxf(fmaxf(col[i], col[i + 1]), col[i + 2]);
    f[i] = ((mx > 0.1f) && pr[i]) ? 1.f : 0.f;
  }
  #pragma unroll
  for (int cc = 0; cc < 4; ++cc) {
    int c = cq * 4 + cc;
    const float4 v = *(const float4*)&mid[b * IMG + c * PLANE + y * WD + x0];
    float4 w;
    w.x = v.x * f[0]; w.y = v.y * f[1]; w.z = v.z * f[2]; w.w = v.w * f[3];
    *(float4*)&out[b * IMG + c * PLANE + y * WD + x0] = w;
  }
}

// ---- cooperative single-dispatch kernel ----
// Phase A: step_a over grid-strided pixel groups. grid.sync.
// Phase B: fmaskzero (in-place dead-pixel zeroing) + NEXT step's threefry
// mask words on the otherwise-idle threads (hides the 23us mask kernel).
// Prologue: wpack + step-0 mask. Epilogue: step_b.
__global__ __launch_bounds__(512) void nca_coop(
    const float* __restrict__ x,
    const float* __restrict__ w1, const float* __restrict__ b1v,
    const float* __restrict__ w2, const float* __restrict__ b2v,
    float* __restrict__ mid0, float* __restrict__ mid1,
    float* __restrict__ mid3c, unsigned char* __restrict__ pre,
    unsigned* __restrict__ mask, float* __restrict__ w1T,
    float* __restrict__ w2T, float* __restrict__ out, Keys keys) {
  cg::grid_group grid = cg::this_grid();
  __shared__ float plds[48][NPIXB];      // 12.3 KB
  __shared__ float red[NPIXB * RROW];    // 16.6 KB

  const int tid = threadIdx.x;
  const unsigned gtid = blockIdx.x * 512u + tid;
  const unsigned nt = gridDim.x * 512u;

  // prologue: mask step 0 (65536 words) + wpack (8192 items)
  for (unsigned t = gtid; t < WORDS_PER_STEP + 8192u; t += nt) {
    if (t < WORDS_PER_STEP) mask_word_body(mask, keys.k[0], keys.k[1], t);
    else wpack_body((int)(t - WORDS_PER_STEP), w1, w2, w1T, w2T);
  }
  grid.sync();

  float* midbuf[2] = {mid0, mid1};
  for (int s = 0; s < NSTEPS; ++s) {
    const float* src = (s == 0) ? x : midbuf[(s - 1) & 1];
    float* mid = midbuf[s & 1];
    for (int grp = blockIdx.x; grp < NGRP; grp += gridDim.x) {
      step_a_body(grp, tid, src, w1T, w2T, b1v, b2v,
                  mask + s * WORDS_PER_STEP, mid, mid3c, pre, plds, red);
      __syncthreads();
    }
    grid.sync();
    if (s < NSTEPS - 1) {
      for (unsigned t = gtid; t < (unsigned)NPIX + WORDS_PER_STEP; t += nt) {
        if (t < (unsigned)NPIX) fmaskzero_body((int)t, mid3c, pre, mid);
        else mask_word_body(mask + (s + 1) * WORDS_PER_STEP,
                            keys.k[2 * (s + 1)], keys.k[2 * (s + 1) + 1],
                            t - (unsigned)NPIX);
      }
      grid.sync();
    }
  }
  for (unsigned t = gtid; t < (unsigned)NPIX; t += nt)
    step_b_body((int)t, midbuf[(NSTEPS - 1) & 1], pre, out);
}

// ---- fallback wrappers (r12 path, used if coop can't co-reside) ----
__global__ __launch_bounds__(256) void mask_kernel(unsigned* __restrict__ mask,
                                                   Keys keys) {
  unsigned t = blockIdx.x * 256u + threadIdx.x;
  unsigned step = t >> 16;
  mask_word_body(mask + step * WORDS_PER_STEP,
                 keys.k[2 * step], keys.k[2 * step + 1], t & 65535u);
}
__global__ __launch_bounds__(256) void wpack_kernel(
    const float* __restrict__ w1, const float* __restrict__ w2,
    float* __restrict__ w1T, float* __restrict__ w2T) {
  wpack_body(blockIdx.x * 256 + threadIdx.x, w1, w2, w1T, w2T);
}
__global__ __launch_bounds__(512) void step_a_kernel(
    const float* __restrict__ s, const float* __restrict__ w1T,
    const float* __restrict__ w2T, const float* __restrict__ bias1,
    const float* __restrict__ bias2, const unsigned* __restrict__ mask,
    float* __restrict__ mid, float* __restrict__ mid3c,
    unsigned char* __restrict__ pre) {
  __shared__ float plds[48][NPIXB];
  __shared__ float red[NPIXB * RROW];
  step_a_body(blockIdx.x, threadIdx.x, s, w1T, w2T, bias1, bias2, mask,
              mid, mid3c, pre, plds, red);
}
__global__ __launch_bounds__(256) void fmaskzero_kernel(
    const float* __restrict__ mid3c, const unsigned char* __restrict__ pre,
    float* __restrict__ mid) {
  fmaskzero_body(blockIdx.x * 256 + threadIdx.x, mid3c, pre, mid);
}
__global__ __launch_bounds__(256) void step_b_kernel(
    const float* __restrict__ mid, const unsigned char* __restrict__ pre,
    float* __restrict__ out) {
  step_b_body(blockIdx.x * 256 + threadIdx.x, mid, pre, out);
}

extern "C" void kernel_launch(void* const* d_in, const int* in_sizes, int n_in,
                              void* d_out, int out_size, void* d_ws, size_t ws_size,
                              hipStream_t stream) {
  const float* x  = (const float*)d_in[0];
  const float* w1 = (const float*)d_in[1];
  const float* b1 = (const float*)d_in[2];
  const float* w2 = (const float*)d_in[3];
  const float* b2 = (const float*)d_in[4];
  float* out = (float*)d_out;

  char* ws = (char*)d_ws;
  float* mid0 = (float*)ws;
  float* mid1 = (float*)(ws + (size_t)NELEM * 4);
  float* mid3c = (float*)(ws + 2 * (size_t)NELEM * 4);
  unsigned char* pre = (unsigned char*)(ws + 2 * (size_t)NELEM * 4
                                           + (size_t)NPIX * 4);
  unsigned* mask = (unsigned*)(ws + 2 * (size_t)NELEM * 4
                                  + (size_t)NPIX * 4 + NPIX);
  float* w1T = (float*)(ws + 2 * (size_t)NELEM * 4 + (size_t)NPIX * 4 + NPIX
                           + (size_t)NSTEPS * WORDS_PER_STEP * 4);
  float* w2T = w1T + 48 * HIDN;

  Keys keys;
  for (int j = 0; j < NSTEPS; ++j) {
    unsigned a, b;
    tf2x32(0u, 42u, 0u, (unsigned)j, a, b);
    keys.k[2 * j] = a; keys.k[2 * j + 1] = b;
  }

  // co-residency check (deterministic -> same path every call; host-only,
  // graph-capture-safe query)
  int occ = 0;
  hipError_t e = hipOccupancyMaxActiveBlocksPerMultiprocessor(
      &occ, nca_coop, 512, 0);
  int grid = (e == hipSuccess) ? occ * 256 : 0;
  if (grid > NGRP) grid = NGRP;

  if (grid >= 256) {
    void* args[] = {
      (void*)&x, (void*)&w1, (void*)&b1, (void*)&w2, (void*)&b2,
      (void*)&mid0, (void*)&mid1, (void*)&mid3c, (void*)&pre, (void*)&mask,
      (void*)&w1T, (void*)&w2T, (void*)&out, (void*)&keys
    };
    hipLaunchCooperativeKernel((const void*)nca_coop, dim3(grid), dim3(512),
                               args, 0, stream);
  } else {
    // fallback: r12's proven multi-kernel sequence
    mask_kernel<<<(NSTEPS * WORDS_PER_STEP) / 256, 256, 0, stream>>>(mask, keys);
    wpack_kernel<<<(48 * HIDN + HIDN * 16) / 256, 256, 0, stream>>>(
        w1, w2, w1T, w2T);
    float* midbuf[2] = {mid0, mid1};
    for (int s = 0; s < NSTEPS; ++s) {
      const float* src = (s == 0) ? x : midbuf[(s - 1) & 1];
      step_a_kernel<<<NGRP, 512, 0, stream>>>(
          src, w1T, w2T, b1, b2, mask + s * WORDS_PER_STEP,
          midbuf[s & 1], mid3c, pre);
      if (s < NSTEPS - 1)
        fmaskzero_kernel<<<NPIX / 256, 256, 0, stream>>>(
            mid3c, pre, midbuf[s & 1]);
    }
    step_b_kernel<<<NPIX / 256, 256, 0, stream>>>(
        midbuf[(NSTEPS - 1) & 1], pre, out);
  }
}

// Round 14
// 377.145 us; speedup vs baseline: 4.1948x; 4.1948x over previous
//
#include <hip/hip_runtime.h>
#include <stdint.h>

// NCA: B=8, C=16, H=W=128, hidden=128, 8 steps. r12 multi-kernel structure
// (coop grid.sync measured ~100us/sync on 8-XCD MI355X — never again).
// ws: [0,8MB) midA, [8MB,16MB) midB, [+512KB) mid3c, [+128KB) pre,
//     [+2MB) mask bits, [+24KB) w1T, [+8KB) w2T. ~18.7 MB.

#define BATCH 8
#define CH 16
#define HT 128
#define WD 128
#define HIDN 128
#define PLANE (HT*WD)
#define IMG (CH*PLANE)
#define NELEM (BATCH*IMG)
#define NPIX (BATCH*PLANE)
#define WORDS_PER_STEP (NELEM/32)   // 65536
#define NSTEPS 8
#define NPIXB 64     // pixels per step_a block (half row)
#define NGRP (NPIX/NPIXB)           // 2048
#define RROW 65      // red row stride: odd -> conflict-free

typedef float v2f __attribute__((ext_vector_type(2)));

__host__ __device__ __forceinline__ unsigned rotl32u(unsigned v, int r) {
  return (v << r) | (v >> (32 - r));
}

// JAX threefry2x32 (20 rounds).
__host__ __device__ __forceinline__ void tf2x32(unsigned k0, unsigned k1,
                                                unsigned c0, unsigned c1,
                                                unsigned &o0, unsigned &o1) {
  const unsigned ks2 = k0 ^ k1 ^ 0x1BD11BDAu;
  unsigned x0 = c0 + k0, x1 = c1 + k1;
  x0 += x1; x1 = rotl32u(x1, 13); x1 ^= x0;
  x0 += x1; x1 = rotl32u(x1, 15); x1 ^= x0;
  x0 += x1; x1 = rotl32u(x1, 26); x1 ^= x0;
  x0 += x1; x1 = rotl32u(x1,  6); x1 ^= x0;
  x0 += k1; x1 += ks2 + 1u;
  x0 += x1; x1 = rotl32u(x1, 17); x1 ^= x0;
  x0 += x1; x1 = rotl32u(x1, 29); x1 ^= x0;
  x0 += x1; x1 = rotl32u(x1, 16); x1 ^= x0;
  x0 += x1; x1 = rotl32u(x1, 24); x1 ^= x0;
  x0 += ks2; x1 += k0 + 2u;
  x0 += x1; x1 = rotl32u(x1, 13); x1 ^= x0;
  x0 += x1; x1 = rotl32u(x1, 15); x1 ^= x0;
  x0 += x1; x1 = rotl32u(x1, 26); x1 ^= x0;
  x0 += x1; x1 = rotl32u(x1,  6); x1 ^= x0;
  x0 += k0; x1 += k1 + 3u;
  x0 += x1; x1 = rotl32u(x1, 17); x1 ^= x0;
  x0 += x1; x1 = rotl32u(x1, 29); x1 ^= x0;
  x0 += x1; x1 = rotl32u(x1, 16); x1 ^= x0;
  x0 += x1; x1 = rotl32u(x1, 24); x1 ^= x0;
  x0 += k1; x1 += ks2 + 4u;
  x0 += x1; x1 = rotl32u(x1, 13); x1 ^= x0;
  x0 += x1; x1 = rotl32u(x1, 15); x1 ^= x0;
  x0 += x1; x1 = rotl32u(x1, 26); x1 ^= x0;
  x0 += x1; x1 = rotl32u(x1,  6); x1 ^= x0;
  x0 += ks2; x1 += k0 + 5u;
  o0 = x0; o1 = x1;
}

__device__ __forceinline__ void mask_word_body(unsigned* __restrict__ mask,
                                               unsigned k0, unsigned k1,
                                               unsigned w) {
  unsigned base = w << 5;
  unsigned word = 0u;
  #pragma unroll 4
  for (int i = 0; i < 32; ++i) {
    unsigned b1x, b2x;
    tf2x32(k0, k1, 0u, base + (unsigned)i, b1x, b2x);
    word |= ((((b1x ^ b2x) >> 9) != 0u) ? 1u : 0u) << i;
  }
  mask[w] = word;
}

// wpack + step-0 mask in one dispatch (kills the serial mask prologue).
__global__ __launch_bounds__(256) void wpack_mask0_kernel(
    const float* __restrict__ w1, const float* __restrict__ w2,
    float* __restrict__ w1T, float* __restrict__ w2T,
    unsigned* __restrict__ mask, unsigned k0, unsigned k1) {
  unsigned t = blockIdx.x * 256u + threadIdx.x;   // 73728 threads
  if (t < WORDS_PER_STEP) {
    mask_word_body(mask, k0, k1, t);
  } else {
    int i = (int)(t - WORDS_PER_STEP);            // 8192 wpack items
    if (i < 48 * HIDN) {
      int c = i >> 7, h = i & 127;
      w1T[i] = w1[h * 48 + c];
    } else {
      int j = i - 48 * HIDN;
      int h = j >> 4, o = j & 15;
      w2T[j] = w2[o * HIDN + h];
    }
  }
}

// Step kernel A — r12's measured-best structure; MLP inner loops on float2
// ext-vectors so LLVM can select v_pk_fma_f32 (fp32 peak is the PACKED
// rate; scalar v_fmac is half-rate — this was ~15us/step of VALU).
// g via readfirstlane (r7 lesson: else weights become per-lane loads).
__global__ __launch_bounds__(512) void step_a_kernel(
    const float* __restrict__ s,
    const float* __restrict__ w1T,   // [48][128]
    const float* __restrict__ w2T,   // [128][16]
    const float* __restrict__ bias1, // [128]
    const float* __restrict__ bias2, // [16]
    const unsigned* __restrict__ mask,
    float* __restrict__ mid,
    float* __restrict__ mid3c,       // ch3 snapshot (for fmaskzero)
    unsigned char* __restrict__ pre) {
  __shared__ float plds[48][NPIXB];      // 12.3 KB, conflict-free columns
  __shared__ float red[NPIXB * RROW];    // 16.6 KB

  const int tid = threadIdx.x;
  const int pix = tid & 63;
  const int g = __builtin_amdgcn_readfirstlane(tid >> 6);  // wave-uniform 0..7
  const int pid = blockIdx.x * NPIXB + pix;
  const int b = pid >> 14;
  const int r = pid & 16383;
  const int y = r >> 7, x = r & 127;

  // ---- perceive: this wave's 2 channels into LDS ----
  const float* sb = s + b * IMG;
  const int ctr = y * WD + x;
  const bool yu = (y > 0), yd = (y < HT - 1), xl = (x > 0), xr = (x < WD - 1);
  float premax = -1e30f;
  #pragma unroll
  for (int cc = 0; cc < 2; ++cc) {
    const int c = 2 * g + cc;
    const float* sc = sb + c * PLANE + ctr;
    float a11 = sc[0];
    float a00 = (yu && xl) ? sc[-WD - 1] : 0.f;
    float a01 = yu         ? sc[-WD]     : 0.f;
    float a02 = (yu && xr) ? sc[-WD + 1] : 0.f;
    float a10 = xl         ? sc[-1]      : 0.f;
    float a12 = xr         ? sc[1]       : 0.f;
    float a20 = (yd && xl) ? sc[WD - 1]  : 0.f;
    float a21 = yd         ? sc[WD]      : 0.f;
    float a22 = (yd && xr) ? sc[WD + 1]  : 0.f;
    plds[c][pix]      = a11;
    plds[16 + c][pix] = (a02 - a00) + 2.f * (a12 - a10) + (a22 - a20);
    plds[32 + c][pix] = (a20 - a00) + 2.f * (a21 - a01) + (a22 - a02);
    if (g == 1 && cc == 1) {           // c == 3, the alive channel
      float m0 = fmaxf(fmaxf(a00, a01), fmaxf(a02, a10));
      float m1 = fmaxf(fmaxf(a11, a12), fmaxf(a20, a21));
      premax = fmaxf(fmaxf(m0, m1), a22);
    }
  }
  __syncthreads();

  // ---- MLP: this wave's 16-hid chunk, packed f32 pairs ----
  v2f t2[8];
  {
    const v2f* b1c = (const v2f*)(bias1 + g * 16);
    #pragma unroll
    for (int j = 0; j < 8; ++j) t2[j] = b1c[j];
  }
  #pragma unroll 2
  for (int c = 0; c < 48; ++c) {
    const float pc = plds[c][pix];             // ds_read_b32, conflict-free
    v2f pc2; pc2.x = pc; pc2.y = pc;
    const v2f* wr = (const v2f*)(w1T + c * HIDN + g * 16); // s_load_dwordx16
    #pragma unroll
    for (int j = 0; j < 8; ++j)
      t2[j] = __builtin_elementwise_fma(pc2, wr[j], t2[j]);  // v_pk_fma_f32
  }
  v2f dx2[8];
  #pragma unroll
  for (int o = 0; o < 8; ++o) { dx2[o].x = 0.f; dx2[o].y = 0.f; }
  const float* t16 = (const float*)t2;
  #pragma unroll
  for (int j = 0; j < 16; ++j) {
    float h = fmaxf(t16[j], 0.f);
    v2f h2; h2.x = h; h2.y = h;
    const v2f* w2r = (const v2f*)(w2T + (g * 16 + j) * 16); // s_load_dwordx16
    #pragma unroll
    for (int o = 0; o < 8; ++o)
      dx2[o] = __builtin_elementwise_fma(h2, w2r[o], dx2[o]);
  }
  const float* dx = (const float*)dx2;

  // ---- two-stage dx reduction in LDS ----
  if (g < 4) {
    #pragma unroll
    for (int o = 0; o < 16; ++o) red[pix * RROW + g * 16 + o] = dx[o];
  }
  __syncthreads();
  if (g >= 4) {
    #pragma unroll
    for (int o = 0; o < 16; ++o) red[pix * RROW + (g - 4) * 16 + o] += dx[o];
  }
  if (g == 1) pre[pid] = (premax > 0.1f) ? 1 : 0;
  __syncthreads();

  // ---- epilogue: 1024 (pix,o) items over 512 threads ----
  #pragma unroll
  for (int k = 0; k < 2; ++k) {
    const int idx = tid + k * 512;
    const int p2 = idx & 63, o = idx >> 6;
    const int pid2 = blockIdx.x * NPIXB + p2;
    const int b2i = pid2 >> 14;
    const int r2 = pid2 & 16383;
    const int y2 = r2 >> 7, x2 = r2 & 127;
    const float* rr = red + p2 * RROW + o;
    float d = ((rr[0] + rr[16]) + (rr[32] + rr[48])) + bias2[o];
    d = fminf(fmaxf(d, -5.f), 5.f);
    unsigned mw = mask[((b2i * 16 + o) * HT + y2) * 4 + (x2 >> 5)];
    float v = plds[o][p2] + (((mw >> (x2 & 31)) & 1u) ? d : 0.f);
    mid[b2i * IMG + o * PLANE + r2] = v;
    if (o == 3) mid3c[pid2] = v;     // ch3 snapshot for fmaskzero
  }
}

// fmaskzero (+ next step's mask words on the same threads): post-alive from
// the ch3 snapshot, AND pre, zero dead pixels IN PLACE (next step_a then
// reads an already-masked state — r12-validated). Each thread with tid<128
// also computes one threefry mask word for step s+1 (~+1.5us, hides the
// 23us serial mask kernel).
__global__ __launch_bounds__(256) void fmaskzero_mask_kernel(
    const float* __restrict__ mid3c,
    const unsigned char* __restrict__ pre,
    float* __restrict__ mid,
    unsigned* __restrict__ mask_next, unsigned k0, unsigned k1) {
  int t = blockIdx.x * 256 + threadIdx.x;   // NPIX
  int b = t >> 14;
  int r = t & 16383;
  int y = r >> 7, x = r & 127;
  const float* m3 = mid3c + b * PLANE;
  float mx = -1e30f;
  #pragma unroll
  for (int dy = -1; dy <= 1; ++dy) {
    int yy = y + dy; if ((unsigned)yy >= HT) continue;
    #pragma unroll
    for (int dxx = -1; dxx <= 1; ++dxx) {
      int xx = x + dxx;
      if ((unsigned)xx < WD) mx = fmaxf(mx, m3[yy * WD + xx]);
    }
  }
  if (!((mx > 0.1f) && pre[t])) {
    float* mp = mid + b * IMG + r;
    #pragma unroll
    for (int c = 0; c < CH; ++c) mp[c * PLANE] = 0.f;
  }
  if (threadIdx.x < 128)   // 512 blocks x 128 = 65536 words
    mask_word_body(mask_next, k0, k1, blockIdx.x * 128u + threadIdx.x);
}

// Final step_b: post-alive maxpool + apply pre&post, 4-way channel split.
__global__ __launch_bounds__(256) void step_b_kernel(
    const float* __restrict__ mid,
    const unsigned char* __restrict__ pre,
    float* __restrict__ out) {
  int t = blockIdx.x * 256 + threadIdx.x;   // NPIX threads
  int cq = t >> 15;
  int qid = t & 32767;
  int b = qid >> 12;
  int r = qid & 4095;
  int y = r >> 5;
  int x0 = (r & 31) * 4;
  const float* m3 = mid + b * IMG + 3 * PLANE;

  float col[6];
  #pragma unroll
  for (int j = 0; j < 6; ++j) {
    int xx = x0 - 1 + j;
    float m = -1e30f;
    if ((unsigned)xx < WD) {
      #pragma unroll
      for (int dy = -1; dy <= 1; ++dy) {
        int yy = y + dy;
        if ((unsigned)yy < HT) m = fmaxf(m, m3[yy * WD + xx]);
      }
    }
    col[j] = m;
  }
  const unsigned char* pr = pre + b * PLANE + y * WD + x0;
  float f[4];
  #pragma unroll
  for (int i = 0; i < 4; ++i) {
    float mx = fmaxf(fmaxf(col[i], col[i + 1]), col[i + 2]);
    f[i] = ((mx > 0.1f) && pr[i]) ? 1.f : 0.f;
  }
  #pragma unroll
  for (int cc = 0; cc < 4; ++cc) {
    int c = cq * 4 + cc;
    const float4 v = *(const float4*)&mid[b * IMG + c * PLANE + y * WD + x0];
    float4 w;
    w.x = v.x * f[0]; w.y = v.y * f[1]; w.z = v.z * f[2]; w.w = v.w * f[3];
    *(float4*)&out[b * IMG + c * PLANE + y * WD + x0] = w;
  }
}

extern "C" void kernel_launch(void* const* d_in, const int* in_sizes, int n_in,
                              void* d_out, int out_size, void* d_ws, size_t ws_size,
                              hipStream_t stream) {
  const float* x  = (const float*)d_in[0];
  const float* w1 = (const float*)d_in[1];
  const float* b1 = (const float*)d_in[2];
  const float* w2 = (const float*)d_in[3];
  const float* b2 = (const float*)d_in[4];
  float* out = (float*)d_out;

  char* ws = (char*)d_ws;
  float* midbuf[2];
  midbuf[0] = (float*)ws;
  midbuf[1] = (float*)(ws + (size_t)NELEM * 4);
  float* mid3c = (float*)(ws + 2 * (size_t)NELEM * 4);
  unsigned char* pre = (unsigned char*)(ws + 2 * (size_t)NELEM * 4
                                           + (size_t)NPIX * 4);
  unsigned* mask = (unsigned*)(ws + 2 * (size_t)NELEM * 4
                                  + (size_t)NPIX * 4 + NPIX);
  float* w1T = (float*)(ws + 2 * (size_t)NELEM * 4 + (size_t)NPIX * 4 + NPIX
                           + (size_t)NSTEPS * WORDS_PER_STEP * 4);
  float* w2T = w1T + 48 * HIDN;

  // keys = jax.random.split(key(42), 8): keys[j] = threefry2x32((0,42),(0,j))
  unsigned keys[2 * NSTEPS];
  for (int j = 0; j < NSTEPS; ++j) {
    unsigned a, b;
    tf2x32(0u, 42u, 0u, (unsigned)j, a, b);
    keys[2 * j] = a; keys[2 * j + 1] = b;
  }

  wpack_mask0_kernel<<<(WORDS_PER_STEP + 8192) / 256, 256, 0, stream>>>(
      w1, w2, w1T, w2T, mask, keys[0], keys[1]);

  for (int s = 0; s < NSTEPS; ++s) {
    const float* src = (s == 0) ? x : midbuf[(s - 1) & 1];
    step_a_kernel<<<NGRP, 512, 0, stream>>>(
        src, w1T, w2T, b1, b2, mask + s * WORDS_PER_STEP,
        midbuf[s & 1], mid3c, pre);
    if (s < NSTEPS - 1)
      fmaskzero_mask_kernel<<<NPIX / 256, 256, 0, stream>>>(
          mid3c, pre, midbuf[s & 1],
          mask + (s + 1) * WORDS_PER_STEP, keys[2 * (s + 1)],
          keys[2 * (s + 1) + 1]);
  }
  step_b_kernel<<<NPIX / 256, 256, 0, stream>>>(
      midbuf[(NSTEPS - 1) & 1], pre, out);
}